// Round 13
// baseline (508.698 us; speedup 1.0000x reference)
//
#include <hip/hip_runtime.h>
#include <math.h>

#define NTOK 8192   // B*S
#define DDIM 1024
#define NEXP 8
#define FDIM 4096
#define MAXROWS 26624   // <=3 active experts/token + per-expert pad-to-256

typedef short bf16x8 __attribute__((ext_vector_type(8)));
typedef float f32x4 __attribute__((ext_vector_type(4)));

#define BAR() asm volatile("s_barrier" ::: "memory")
#define WAITV(n) asm volatile("s_waitcnt vmcnt(" #n ")" ::: "memory")

static __device__ __forceinline__ unsigned short f2bf(float f) {
  unsigned int u = __float_as_uint(f);
  u += 0x7fffu + ((u >> 16) & 1u);
  return (unsigned short)(u >> 16);
}
static __device__ __forceinline__ float bf2f(unsigned short b) {
  return __uint_as_float(((unsigned int)b) << 16);
}

static __device__ __forceinline__ void gl_lds16(const void* g, void* l) {
  __builtin_amdgcn_global_load_lds(
      (const __attribute__((address_space(1))) unsigned int*)g,
      (__attribute__((address_space(3))) unsigned int*)l, 16, 0, 0);
}

// tanh-form gelu via exp2 (max abs err ~4e-4 vs erf form)
static __device__ __forceinline__ float gelu_f(float v) {
  float x2 = v * v;
  float p = fmaf(x2, 0.10294422f, 2.3021183f);
  float E = __builtin_amdgcn_exp2f(v * p);
  return v - v * __builtin_amdgcn_rcpf(E + 1.f);
}

// ---------------- router (fp32, mask-exact) ----------------
__global__ __launch_bounds__(256) void router_kernel(
    const float* __restrict__ x, const float* __restrict__ prev,
    const float* __restrict__ Wt, const float* __restrict__ Wgt,
    const float* __restrict__ Wel,
    float* __restrict__ gn, float* __restrict__ logits_out)
{
  __shared__ float wt_s[NEXP * DDIM];
  const int tid = threadIdx.x;
  for (int i = tid; i < NEXP * DDIM; i += 256) wt_s[i] = Wt[i];
  __syncthreads();
  const int lane = tid & 63;
  const int t = blockIdx.x * 4 + (tid >> 6);

  const float* xr = x + (size_t)t * DDIM;
  float acc[NEXP];
#pragma unroll
  for (int e = 0; e < NEXP; ++e) acc[e] = 0.f;
  for (int k = lane; k < DDIM; k += 64) {
    float xv = xr[k];
#pragma unroll
    for (int e = 0; e < NEXP; ++e) acc[e] += xv * wt_s[e * DDIM + k];
  }
#pragma unroll
  for (int e = 0; e < NEXP; ++e) {
    float v = acc[e];
#pragma unroll
    for (int off = 32; off >= 1; off >>= 1) v += __shfl_xor(v, off);
    acc[e] = v;
  }
  float pl[NEXP];
#pragma unroll
  for (int e = 0; e < NEXP; ++e) pl[e] = prev[(size_t)t * NEXP + e];
#pragma unroll
  for (int e = 0; e < NEXP; ++e) {
    float s = acc[e];
#pragma unroll
    for (int e2 = 0; e2 < NEXP; ++e2) s += pl[e2] * Wgt[e * NEXP + e2];
    acc[e] = s;
  }
  float mx = acc[0];
#pragma unroll
  for (int e = 1; e < NEXP; ++e) mx = fmaxf(mx, acc[e]);
  float st[NEXP]; float se = 0.f;
#pragma unroll
  for (int e = 0; e < NEXP; ++e) { st[e] = expf(acc[e] - mx); se += st[e]; }
  float inv = 1.f / se;
  float g[NEXP]; float gs = 0.f;
#pragma unroll
  for (int e = 0; e < NEXP; ++e) {
    float s = st[e] * inv;
    float we = 1.f / (1.f + expf(-Wel[e]));
    float gg = (s > 0.5f * we) ? s : 0.f;
    g[e] = gg; gs += gg;
  }
  float r = 1.f / (gs + 1e-6f);
  if (lane < NEXP) {
    gn[(size_t)t * NEXP + lane] = g[lane] * r;
    logits_out[(size_t)t * NEXP + lane] = acc[lane];
  }
}

// ---------------- x f32 -> bf16 ----------------
__global__ __launch_bounds__(256) void cast_kernel(
    const float* __restrict__ in, unsigned short* __restrict__ out)
{
  size_t i = ((size_t)blockIdx.x * 256 + threadIdx.x) * 8;
  float4 a = *(const float4*)(in + i);
  float4 b = *(const float4*)(in + i + 4);
  unsigned short tb[8];
  tb[0]=f2bf(a.x); tb[1]=f2bf(a.y); tb[2]=f2bf(a.z); tb[3]=f2bf(a.w);
  tb[4]=f2bf(b.x); tb[5]=f2bf(b.y); tb[6]=f2bf(b.z); tb[7]=f2bf(b.w);
  *(uint4*)(out + i) = *(const uint4*)tb;
}

// ---------------- count active tokens per expert ----------------
__global__ __launch_bounds__(256) void count_kernel(
    const float* __restrict__ gn, int* __restrict__ cnt)
{
  const int e = blockIdx.x, tid = threadIdx.x;
  int c = 0;
  for (int t = tid; t < NTOK; t += 256) c += (gn[(size_t)t * NEXP + e] > 0.f) ? 1 : 0;
#pragma unroll
  for (int o = 32; o >= 1; o >>= 1) c += __shfl_xor(c, o);
  __shared__ int sm[4];
  if ((tid & 63) == 0) sm[tid >> 6] = c;
  __syncthreads();
  if (tid == 0) cnt[e] = sm[0] + sm[1] + sm[2] + sm[3];
}

// ---------------- compact token lists (deterministic, token order; pad 256) ----------------
__global__ __launch_bounds__(256) void compact_kernel(
    const float* __restrict__ gn, const int* __restrict__ cnt,
    int* __restrict__ offs, int* __restrict__ rowtok, int* __restrict__ rowof)
{
  const int e = blockIdx.x, tid = threadIdx.x;
  int base = 0;
#pragma unroll
  for (int q = 0; q < 8; ++q) if (q < e) base += (cnt[q] + 255) & ~255;
  const int padcnt = (cnt[e] + 255) & ~255;
  if (e == 0 && tid == 0) {
    int a = 0; offs[0] = 0;
#pragma unroll
    for (int q = 0; q < 8; ++q) { a += (cnt[q] + 255) & ~255; offs[q + 1] = a; }
  }
  __shared__ int wsm[4];
  __shared__ int running;
  if (tid == 0) running = 0;
  __syncthreads();
  const int lane = tid & 63, wv = tid >> 6;
  for (int c0 = 0; c0 < NTOK; c0 += 256) {
    const int t = c0 + tid;
    const bool pr = gn[(size_t)t * NEXP + e] > 0.f;
    unsigned long long bal = __ballot(pr);
    int pre = __popcll(bal & ((1ull << lane) - 1ull));
    if (lane == 0) wsm[wv] = __popcll(bal);
    __syncthreads();
    int wbase = 0;
#pragma unroll
    for (int q = 0; q < 4; ++q) if (q < wv) wbase += wsm[q];
    const int tot = wsm[0] + wsm[1] + wsm[2] + wsm[3];
    const int idx = base + running + wbase + pre;
    if (pr) rowtok[idx] = t;
    rowof[(size_t)t * NEXP + e] = pr ? idx : -1;
    __syncthreads();
    if (tid == 0) running += tot;
  }
  __syncthreads();
  for (int i = cnt[e] + tid; i < padcnt; i += 256) rowtok[base + i] = -1;
}

// ---------------- y := sum_e gn*b2 (per-expert fallback path) ----------------
__global__ __launch_bounds__(256) void y_init_kernel(
    const float* __restrict__ gn, const float* __restrict__ b2,
    float* __restrict__ y)
{
  const int t = blockIdx.y;
  const int d = blockIdx.x * 256 + threadIdx.x;
  float s = 0.f;
#pragma unroll
  for (int e = 0; e < NEXP; ++e) s += gn[(size_t)t * NEXP + e] * b2[(size_t)e * DDIM + d];
  y[(size_t)t * DDIM + d] = s;
}

// ---------------- transpose+convert: in f32 [Kin][Nin] -> out bf16 [Nin][Kin] ----------------
__global__ __launch_bounds__(256) void transcvt(
    const float* __restrict__ in, unsigned short* __restrict__ out,
    int Kin, int Nin)
{
  __shared__ float tile[64][65];
  const size_t zo = (size_t)blockIdx.z * Kin * Nin;
  const float* inp = in + zo;
  unsigned short* outp = out + zo;
  const int k0 = blockIdx.y * 64, n0 = blockIdx.x * 64;
  const int tid = threadIdx.x;
  const int r = tid >> 4, c4 = (tid & 15) * 4;
#pragma unroll
  for (int rr = 0; rr < 64; rr += 16) {
    float4 v = *(const float4*)(inp + (size_t)(k0 + r + rr) * Nin + n0 + c4);
    tile[r + rr][c4] = v.x; tile[r + rr][c4 + 1] = v.y;
    tile[r + rr][c4 + 2] = v.z; tile[r + rr][c4 + 3] = v.w;
  }
  __syncthreads();
#pragma unroll
  for (int it = 0; it < 2; ++it) {
    const int o = it * 256 + tid;
    const int n = o >> 3, ks = (o & 7) * 8;
    unsigned short tb[8];
#pragma unroll
    for (int j = 0; j < 8; ++j) tb[j] = f2bf(tile[ks + j][n]);
    *(uint4*)(outp + (size_t)(n0 + n) * Kin + k0 + ks) = *(const uint4*)tb;
  }
}

// ===================== 256x256 4-phase GEMM kernels (grouped path) =====================
// 512 threads = 8 waves (2M x 4N); wave tile 128x64; acc[8][4]; BK=64.
// LDS: As/Bs [2][256*64] bf16 = 128 KB double-buffered.
// XOR swizzle: 16B-group slot = g ^ (row&7); gl_lds dest linear, SOURCE inverse-swizzled
// (verified: 0 bank conflicts). NO XCD swizzle (R8-R11: 2x regression on this grid).
// R13 change vs R12 (single variable): staging order within the tile is now
// P1:{A0,A1,B0,B1}+vmcnt(4) | P2:{A2,A3} | P3:{B2,B3} | P4:{} — the newest load the
// boundary wait depends on (B2,B3, issued at P3 of t-1) gains a full extra MFMA
// quadrant of slack vs R12's P4-issued stages; 4 loads stay in flight across the barrier.

// ---------------- GEMM1: h' = gn * gelu(gather(xb) @ W1^T + b1) -> hb bf16 ----------------
__global__ __launch_bounds__(512, 2) void gemm_h256(
    const unsigned short* __restrict__ xb,   // [NTOK][DDIM] bf16
    const unsigned short* __restrict__ W,    // [E][FDIM][DDIM] bf16 (transposed)
    const float* __restrict__ b1,            // [E][FDIM]
    const float* __restrict__ gn,            // [NTOK][E]
    const int* __restrict__ rowtok,
    const int* __restrict__ offs,            // [9], multiples of 256
    unsigned short* __restrict__ hb)         // [MAXROWS][FDIM] bf16
{
  __shared__ unsigned short As[2][256 * 64];
  __shared__ unsigned short Bs[2][256 * 64];
  __shared__ float gns[256];
  __shared__ float b1s[256];
  __shared__ int toks[256];
  const int tid = threadIdx.x;
  const int r0 = blockIdx.y * 256;
  if (r0 >= offs[8]) return;
  int e = 0;
#pragma unroll
  for (int q = 1; q < 8; ++q) if (r0 >= offs[q]) e = q;
  const int n0 = blockIdx.x * 256;
  const unsigned short* We = W + (size_t)e * FDIM * DDIM;

  if (tid < 256) {
    const int tk = rowtok[r0 + tid];
    toks[tid] = tk;
    gns[tid] = (tk >= 0) ? gn[(size_t)tk * NEXP + e] : 0.f;
    b1s[tid] = b1[(size_t)e * FDIM + n0 + tid];
  }
  __syncthreads();

  // staging: thread -> (chunk row rc, lds group gld); source group inverse-swizzled
  const int rc = tid >> 3;
  const int gld = tid & 7;
  const int gsrc = gld ^ (rc & 7);
  const unsigned short* aP[4];
  const unsigned short* bP[4];
#pragma unroll
  for (int c = 0; c < 4; ++c) {
    int tk = toks[c * 64 + rc]; if (tk < 0) tk = 0;
    aP[c] = xb + (size_t)tk * DDIM + gsrc * 8;
    bP[c] = We + (size_t)(n0 + c * 64 + rc) * DDIM + gsrc * 8;
  }

  const int lane = tid & 63;
  const int wid = tid >> 6;
  const int wm = (wid >> 2) * 128;
  const int wn = (wid & 3) * 64;
  const int fr = lane & 15;
  const int q4 = lane >> 4;

  f32x4 acc[8][4];
#pragma unroll
  for (int i = 0; i < 8; ++i)
#pragma unroll
    for (int j = 0; j < 4; ++j) acc[i][j] = (f32x4){0.f, 0.f, 0.f, 0.f};

  auto stA = [&](int kt, int b, int c) { gl_lds16(aP[c] + kt * 64, &As[b][c * 4096 + tid * 8]); };
  auto stB = [&](int kt, int b, int c) { gl_lds16(bP[c] + kt * 64, &Bs[b][c * 4096 + tid * 8]); };
  auto rdA = [&](int cur, int i, int kk) -> bf16x8 {
    const int row = wm + i * 16 + fr;
    const int sl = (kk * 4 + q4) ^ (row & 7);
    return *(const bf16x8*)&As[cur][row * 64 + sl * 8];
  };
  auto rdB = [&](int cur, int j, int kk) -> bf16x8 {
    const int row = wn + j * 16 + fr;
    const int sl = (kk * 4 + q4) ^ (row & 7);
    return *(const bf16x8*)&Bs[cur][row * 64 + sl * 8];
  };

  const int NT = DDIM / 64;   // 16
  bf16x8 aX[4][2], aY[4][2], bb[2][2];

#pragma unroll
  for (int c = 0; c < 4; ++c) { stA(0, 0, c); stB(0, 0, c); }
  WAITV(0); BAR();

  for (int t = 0; t < NT - 1; ++t) {
    const int cur = t & 1, nxt = cur ^ 1;
    // P1: stage 4 (A0,A1,B0,B1 of t+1) | counted vmcnt(4) on tile t | MFMA A0xB0
    stA(t + 1, nxt, 0); stA(t + 1, nxt, 1);
    stB(t + 1, nxt, 0); stB(t + 1, nxt, 1);
    WAITV(4); BAR();
#pragma unroll
    for (int i = 0; i < 4; ++i) { aX[i][0] = rdA(cur, i, 0); aX[i][1] = rdA(cur, i, 1); }
#pragma unroll
    for (int j = 0; j < 2; ++j) { bb[j][0] = rdB(cur, j, 0); bb[j][1] = rdB(cur, j, 1); }
    __builtin_amdgcn_s_setprio(1);
#pragma unroll
    for (int i = 0; i < 4; ++i)
#pragma unroll
      for (int j = 0; j < 2; ++j)
#pragma unroll
        for (int kk = 0; kk < 2; ++kk)
          acc[i][j] = __builtin_amdgcn_mfma_f32_16x16x32_bf16(aX[i][kk], bb[j][kk], acc[i][j], 0, 0, 0);
    __builtin_amdgcn_s_setprio(0);
    // P2: stage 2 (A2,A3) | read A1 | MFMA A1xB0
    stA(t + 1, nxt, 2); stA(t + 1, nxt, 3);
#pragma unroll
    for (int i = 0; i < 4; ++i) { aY[i][0] = rdA(cur, 4 + i, 0); aY[i][1] = rdA(cur, 4 + i, 1); }
    __builtin_amdgcn_s_setprio(1);
#pragma unroll
    for (int i = 0; i < 4; ++i)
#pragma unroll
      for (int j = 0; j < 2; ++j)
#pragma unroll
        for (int kk = 0; kk < 2; ++kk)
          acc[4 + i][j] = __builtin_amdgcn_mfma_f32_16x16x32_bf16(aY[i][kk], bb[j][kk], acc[4 + i][j], 0, 0, 0);
    __builtin_amdgcn_s_setprio(0);
    // P3: stage 2 (B2,B3) | read B1 | MFMA A1xB1
    stB(t + 1, nxt, 2); stB(t + 1, nxt, 3);
#pragma unroll
    for (int j = 0; j < 2; ++j) { bb[j][0] = rdB(cur, 2 + j, 0); bb[j][1] = rdB(cur, 2 + j, 1); }
    __builtin_amdgcn_s_setprio(1);
#pragma unroll
    for (int i = 0; i < 4; ++i)
#pragma unroll
      for (int j = 0; j < 2; ++j)
#pragma unroll
        for (int kk = 0; kk < 2; ++kk)
          acc[4 + i][2 + j] = __builtin_amdgcn_mfma_f32_16x16x32_bf16(aY[i][kk], bb[j][kk], acc[4 + i][2 + j], 0, 0, 0);
    __builtin_amdgcn_s_setprio(0);
    // P4: MFMA A0xB1 | release barrier
    __builtin_amdgcn_s_setprio(1);
#pragma unroll
    for (int i = 0; i < 4; ++i)
#pragma unroll
      for (int j = 0; j < 2; ++j)
#pragma unroll
        for (int kk = 0; kk < 2; ++kk)
          acc[i][2 + j] = __builtin_amdgcn_mfma_f32_16x16x32_bf16(aX[i][kk], bb[j][kk], acc[i][2 + j], 0, 0, 0);
    __builtin_amdgcn_s_setprio(0);
    BAR();
  }
  // tail tile (no staging)
  {
    const int cur = (NT - 1) & 1;
    WAITV(0); BAR();
#pragma unroll
    for (int i = 0; i < 4; ++i) { aX[i][0] = rdA(cur, i, 0); aX[i][1] = rdA(cur, i, 1); }
#pragma unroll
    for (int i = 0; i < 4; ++i) { aY[i][0] = rdA(cur, 4 + i, 0); aY[i][1] = rdA(cur, 4 + i, 1); }
#pragma unroll
    for (int j = 0; j < 2; ++j) { bb[j][0] = rdB(cur, j, 0); bb[j][1] = rdB(cur, j, 1); }
#pragma unroll
    for (int i = 0; i < 4; ++i)
#pragma unroll
      for (int j = 0; j < 2; ++j)
#pragma unroll
        for (int kk = 0; kk < 2; ++kk) {
          acc[i][j] = __builtin_amdgcn_mfma_f32_16x16x32_bf16(aX[i][kk], bb[j][kk], acc[i][j], 0, 0, 0);
          acc[4 + i][j] = __builtin_amdgcn_mfma_f32_16x16x32_bf16(aY[i][kk], bb[j][kk], acc[4 + i][j], 0, 0, 0);
        }
#pragma unroll
    for (int j = 0; j < 2; ++j) { bb[j][0] = rdB(cur, 2 + j, 0); bb[j][1] = rdB(cur, 2 + j, 1); }
#pragma unroll
    for (int i = 0; i < 4; ++i)
#pragma unroll
      for (int j = 0; j < 2; ++j)
#pragma unroll
        for (int kk = 0; kk < 2; ++kk) {
          acc[i][2 + j] = __builtin_amdgcn_mfma_f32_16x16x32_bf16(aX[i][kk], bb[j][kk], acc[i][2 + j], 0, 0, 0);
          acc[4 + i][2 + j] = __builtin_amdgcn_mfma_f32_16x16x32_bf16(aY[i][kk], bb[j][kk], acc[4 + i][2 + j], 0, 0, 0);
        }
  }

#pragma unroll
  for (int i = 0; i < 8; ++i)
#pragma unroll
    for (int rr = 0; rr < 4; ++rr) {
      const int row = wm + i * 16 + q4 * 4 + rr;
      const int tk = toks[row];
      if (tk < 0) continue;
      const float gv = gns[row];
      unsigned short* hrow = hb + (size_t)(r0 + row) * FDIM + n0;
#pragma unroll
      for (int j = 0; j < 4; ++j) {
        const int col = wn + j * 16 + fr;
        hrow[col] = f2bf(gelu_f(acc[i][j][rr] + b1s[col]) * gv);
      }
    }
}

// ---------------- GEMM2: hb2 = hb @ W2^T (bf16 partials, grouped) ----------------
__global__ __launch_bounds__(512, 2) void gemm_o256(
    const unsigned short* __restrict__ hb,   // [MAXROWS][FDIM] bf16
    const unsigned short* __restrict__ W,    // [E][DDIM][FDIM] bf16 (transposed)
    const int* __restrict__ offs,
    unsigned short* __restrict__ hb2)        // [MAXROWS][DDIM] bf16
{
  __shared__ unsigned short As[2][256 * 64];
  __shared__ unsigned short Bs[2][256 * 64];
  const int tid = threadIdx.x;
  const int r0 = blockIdx.y * 256;
  if (r0 >= offs[8]) return;
  int e = 0;
#pragma unroll
  for (int q = 1; q < 8; ++q) if (r0 >= offs[q]) e = q;
  const int n0 = blockIdx.x * 256;
  const unsigned short* We = W + (size_t)e * FDIM * DDIM;

  const int rc = tid >> 3;
  const int gld = tid & 7;
  const int gsrc = gld ^ (rc & 7);
  const unsigned short* aP[4];
  const unsigned short* bP[4];
#pragma unroll
  for (int c = 0; c < 4; ++c) {
    aP[c] = hb + (size_t)(r0 + c * 64 + rc) * FDIM + gsrc * 8;
    bP[c] = We + (size_t)(n0 + c * 64 + rc) * FDIM + gsrc * 8;
  }

  const int lane = tid & 63;
  const int wid = tid >> 6;
  const int wm = (wid >> 2) * 128;
  const int wn = (wid & 3) * 64;
  const int fr = lane & 15;
  const int q4 = lane >> 4;

  f32x4 acc[8][4];
#pragma unroll
  for (int i = 0; i < 8; ++i)
#pragma unroll
    for (int j = 0; j < 4; ++j) acc[i][j] = (f32x4){0.f, 0.f, 0.f, 0.f};

  auto stA = [&](int kt, int b, int c) { gl_lds16(aP[c] + kt * 64, &As[b][c * 4096 + tid * 8]); };
  auto stB = [&](int kt, int b, int c) { gl_lds16(bP[c] + kt * 64, &Bs[b][c * 4096 + tid * 8]); };
  auto rdA = [&](int cur, int i, int kk) -> bf16x8 {
    const int row = wm + i * 16 + fr;
    const int sl = (kk * 4 + q4) ^ (row & 7);
    return *(const bf16x8*)&As[cur][row * 64 + sl * 8];
  };
  auto rdB = [&](int cur, int j, int kk) -> bf16x8 {
    const int row = wn + j * 16 + fr;
    const int sl = (kk * 4 + q4) ^ (row & 7);
    return *(const bf16x8*)&Bs[cur][row * 64 + sl * 8];
  };

  const int NT = FDIM / 64;   // 64
  bf16x8 aX[4][2], aY[4][2], bb[2][2];

#pragma unroll
  for (int c = 0; c < 4; ++c) { stA(0, 0, c); stB(0, 0, c); }
  WAITV(0); BAR();

  for (int t = 0; t < NT - 1; ++t) {
    const int cur = t & 1, nxt = cur ^ 1;
    stA(t + 1, nxt, 0); stA(t + 1, nxt, 1);
    stB(t + 1, nxt, 0); stB(t + 1, nxt, 1);
    WAITV(4); BAR();
#pragma unroll
    for (int i = 0; i < 4; ++i) { aX[i][0] = rdA(cur, i, 0); aX[i][1] = rdA(cur, i, 1); }
#pragma unroll
    for (int j = 0; j < 2; ++j) { bb[j][0] = rdB(cur, j, 0); bb[j][1] = rdB(cur, j, 1); }
    __builtin_amdgcn_s_setprio(1);
#pragma unroll
    for (int i = 0; i < 4; ++i)
#pragma unroll
      for (int j = 0; j < 2; ++j)
#pragma unroll
        for (int kk = 0; kk < 2; ++kk)
          acc[i][j] = __builtin_amdgcn_mfma_f32_16x16x32_bf16(aX[i][kk], bb[j][kk], acc[i][j], 0, 0, 0);
    __builtin_amdgcn_s_setprio(0);
    stA(t + 1, nxt, 2); stA(t + 1, nxt, 3);
#pragma unroll
    for (int i = 0; i < 4; ++i) { aY[i][0] = rdA(cur, 4 + i, 0); aY[i][1] = rdA(cur, 4 + i, 1); }
    __builtin_amdgcn_s_setprio(1);
#pragma unroll
    for (int i = 0; i < 4; ++i)
#pragma unroll
      for (int j = 0; j < 2; ++j)
#pragma unroll
        for (int kk = 0; kk < 2; ++kk)
          acc[4 + i][j] = __builtin_amdgcn_mfma_f32_16x16x32_bf16(aY[i][kk], bb[j][kk], acc[4 + i][j], 0, 0, 0);
    __builtin_amdgcn_s_setprio(0);
    stB(t + 1, nxt, 2); stB(t + 1, nxt, 3);
#pragma unroll
    for (int j = 0; j < 2; ++j) { bb[j][0] = rdB(cur, 2 + j, 0); bb[j][1] = rdB(cur, 2 + j, 1); }
    __builtin_amdgcn_s_setprio(1);
#pragma unroll
    for (int i = 0; i < 4; ++i)
#pragma unroll
      for (int j = 0; j < 2; ++j)
#pragma unroll
        for (int kk = 0; kk < 2; ++kk)
          acc[4 + i][2 + j] = __builtin_amdgcn_mfma_f32_16x16x32_bf16(aY[i][kk], bb[j][kk], acc[4 + i][2 + j], 0, 0, 0);
    __builtin_amdgcn_s_setprio(0);
    __builtin_amdgcn_s_setprio(1);
#pragma unroll
    for (int i = 0; i < 4; ++i)
#pragma unroll
      for (int j = 0; j < 2; ++j)
#pragma unroll
        for (int kk = 0; kk < 2; ++kk)
          acc[i][2 + j] = __builtin_amdgcn_mfma_f32_16x16x32_bf16(aX[i][kk], bb[j][kk], acc[i][2 + j], 0, 0, 0);
    __builtin_amdgcn_s_setprio(0);
    BAR();
  }
  {
    const int cur = (NT - 1) & 1;
    WAITV(0); BAR();
#pragma unroll
    for (int i = 0; i < 4; ++i) { aX[i][0] = rdA(cur, i, 0); aX[i][1] = rdA(cur, i, 1); }
#pragma unroll
    for (int i = 0; i < 4; ++i) { aY[i][0] = rdA(cur, 4 + i, 0); aY[i][1] = rdA(cur, 4 + i, 1); }
#pragma unroll
    for (int j = 0; j < 2; ++j) { bb[j][0] = rdB(cur, j, 0); bb[j][1] = rdB(cur, j, 1); }
#pragma unroll
    for (int i = 0; i < 4; ++i)
#pragma unroll
      for (int j = 0; j < 2; ++j)
#pragma unroll
        for (int kk = 0; kk < 2; ++kk) {
          acc[i][j] = __builtin_amdgcn_mfma_f32_16x16x32_bf16(aX[i][kk], bb[j][kk], acc[i][j], 0, 0, 0);
          acc[4 + i][j] = __builtin_amdgcn_mfma_f32_16x16x32_bf16(aY[i][kk], bb[j][kk], acc[4 + i][j], 0, 0, 0);
        }
#pragma unroll
    for (int j = 0; j < 2; ++j) { bb[j][0] = rdB(cur, 2 + j, 0); bb[j][1] = rdB(cur, 2 + j, 1); }
#pragma unroll
    for (int i = 0; i < 4; ++i)
#pragma unroll
      for (int j = 0; j < 2; ++j)
#pragma unroll
        for (int kk = 0; kk < 2; ++kk) {
          acc[i][2 + j] = __builtin_amdgcn_mfma_f32_16x16x32_bf16(aX[i][kk], bb[j][kk], acc[i][2 + j], 0, 0, 0);
          acc[4 + i][2 + j] = __builtin_amdgcn_mfma_f32_16x16x32_bf16(aY[i][kk], bb[j][kk], acc[4 + i][2 + j], 0, 0, 0);
        }
  }

#pragma unroll
  for (int i = 0; i < 8; ++i)
#pragma unroll
    for (int rr = 0; rr < 4; ++rr) {
      const int row = wm + i * 16 + q4 * 4 + rr;
      unsigned short* orow = hb2 + (size_t)(r0 + row) * DDIM + n0;
#pragma unroll
      for (int j = 0; j < 4; ++j) {
        const int col = wn + j * 16 + fr;
        orow[col] = f2bf(acc[i][j][rr]);
      }
    }
}

// ---------------- combine: y = sum over active rows (bf16 partials) + gn*b2 ----------------
__global__ __launch_bounds__(256) void combine_kernel(
    const unsigned short* __restrict__ hb2, const int* __restrict__ rowof,
    const float* __restrict__ gn, const float* __restrict__ b2,
    float* __restrict__ y)
{
  const int t = blockIdx.y;
  const int d = blockIdx.x * 256 + threadIdx.x;
  float s = 0.f;
#pragma unroll
  for (int e = 0; e < NEXP; ++e) {
    s += gn[(size_t)t * NEXP + e] * b2[(size_t)e * DDIM + d];
    const int r = rowof[(size_t)t * NEXP + e];
    if (r >= 0) s += bf2f(hb2[(size_t)r * DDIM + d]);
  }
  y[(size_t)t * DDIM + d] = s;
}

// ===================== 128x128 fallback kernels (tier-B, per-expert) =====================
__global__ __launch_bounds__(128, 2) void gemm_h128(
    const unsigned short* __restrict__ xb,
    const unsigned short* __restrict__ W,
    const float* __restrict__ b1,
    const float* __restrict__ gn,
    const int* __restrict__ rowtok,
    const int* __restrict__ offs,
    int efix,
    unsigned short* __restrict__ hb)
{
  __shared__ unsigned short As[2][4096];
  __shared__ unsigned short Bs[2][4096];
  __shared__ float gns[128];
  __shared__ float b1s[128];
  __shared__ int toks[128];
  const int tid = threadIdx.x;
  const int e = efix;
  const int hbase = offs[e];
  const int mt = (hbase >> 7) + blockIdx.y;
  if (mt * 128 >= offs[e + 1]) return;
  const int n0 = blockIdx.x * 128;
  const unsigned short* We = W;

  {
    const int tk = rowtok[mt * 128 + tid];
    toks[tid] = tk;
    gns[tid] = (tk >= 0) ? gn[(size_t)tk * NEXP + e] : 0.f;
    b1s[tid] = b1[(size_t)e * FDIM + n0 + tid];
  }
  __syncthreads();

  const int st_row = tid >> 2;
  const int st_off = (((tid & 3) ^ (st_row & 3)) << 3);
  const unsigned short* aP[4];
  const unsigned short* bP[4];
#pragma unroll
  for (int i = 0; i < 4; ++i) {
    int tk = toks[i * 32 + st_row]; if (tk < 0) tk = 0;
    aP[i] = xb + (size_t)tk * DDIM + st_off;
    bP[i] = We + (size_t)(n0 + i * 32 + st_row) * DDIM + st_off;
  }
  const int ldst = tid * 8;
  const int lane = tid & 63;
  const int w = tid >> 6;
  const int fr = lane & 15;
  const int rdoff = (((lane >> 4) ^ (lane & 3)) << 3);

  f32x4 acc[8][4];
#pragma unroll
  for (int i = 0; i < 8; ++i)
#pragma unroll
    for (int j = 0; j < 4; ++j) acc[i][j] = (f32x4){0.f, 0.f, 0.f, 0.f};

  auto stage = [&](int kt, int b) {
    const int ke = kt * 32;
#pragma unroll
    for (int i = 0; i < 4; ++i) {
      gl_lds16(aP[i] + ke, &As[b][i * 1024 + ldst]);
      gl_lds16(bP[i] + ke, &Bs[b][i * 1024 + ldst]);
    }
  };

  const int NT = DDIM / 32;
  stage(0, 0);
  asm volatile("s_waitcnt vmcnt(0) lgkmcnt(0)" ::: "memory"); BAR();
  for (int t = 0; t < NT; ++t) {
    const int cur = t & 1;
    if (t + 1 < NT) stage(t + 1, cur ^ 1);
    bf16x8 af[8], bfv[4];
#pragma unroll
    for (int i = 0; i < 8; ++i) af[i] = *(const bf16x8*)&As[cur][(i * 16 + fr) * 32 + rdoff];
#pragma unroll
    for (int j = 0; j < 4; ++j) bfv[j] = *(const bf16x8*)&Bs[cur][(w * 64 + j * 16 + fr) * 32 + rdoff];
#pragma unroll
    for (int i = 0; i < 8; ++i)
#pragma unroll
      for (int j = 0; j < 4; ++j)
        acc[i][j] = __builtin_amdgcn_mfma_f32_16x16x32_bf16(af[i], bfv[j], acc[i][j], 0, 0, 0);
    if (t + 1 < NT) { asm volatile("s_waitcnt vmcnt(0) lgkmcnt(0)" ::: "memory"); BAR(); }
  }
#pragma unroll
  for (int i = 0; i < 8; ++i)
#pragma unroll
    for (int r = 0; r < 4; ++r) {
      const int row = i * 16 + (lane >> 4) * 4 + r;
      const int tk = toks[row];
      if (tk < 0) continue;
      const float gv = gns[row];
      unsigned short* hrow = hb + (size_t)(mt * 128 + row - hbase) * FDIM + n0;
#pragma unroll
      for (int j = 0; j < 4; ++j) {
        const int col = w * 64 + j * 16 + fr;
        hrow[col] = f2bf(gelu_f(acc[i][j][r] + b1s[col]) * gv);
      }
    }
}

__global__ __launch_bounds__(128, 2) void gemm_o128(
    const unsigned short* __restrict__ hb,
    const unsigned short* __restrict__ W,
    const int* __restrict__ rowtok,
    const int* __restrict__ offs,
    int efix,
    float* __restrict__ yout)
{
  __shared__ unsigned short As[2][4096];
  __shared__ unsigned short Bs[2][4096];
  __shared__ int toks[128];
  const int tid = threadIdx.x;
  const int e = efix;
  const int hbase = offs[e];
  const int mt = (hbase >> 7) + blockIdx.y;
  if (mt * 128 >= offs[e + 1]) return;
  const int n0 = blockIdx.x * 128;

  toks[tid] = rowtok[mt * 128 + tid];
  __syncthreads();

  const int st_row = tid >> 2;
  const int st_off = (((tid & 3) ^ (st_row & 3)) << 3);
  const unsigned short* aP[4];
  const unsigned short* bP[4];
#pragma unroll
  for (int i = 0; i < 4; ++i) {
    aP[i] = hb + (size_t)(mt * 128 - hbase + i * 32 + st_row) * FDIM + st_off;
    bP[i] = W + (size_t)(n0 + i * 32 + st_row) * FDIM + st_off;
  }
  const int ldst = tid * 8;
  const int lane = tid & 63;
  const int w = tid >> 6;
  const int fr = lane & 15;
  const int rdoff = (((lane >> 4) ^ (lane & 3)) << 3);

  f32x4 acc[8][4];
#pragma unroll
  for (int i = 0; i < 8; ++i)
#pragma unroll
    for (int j = 0; j < 4; ++j) acc[i][j] = (f32x4){0.f, 0.f, 0.f, 0.f};

  auto stage = [&](int kt, int b) {
    const int ke = kt * 32;
#pragma unroll
    for (int i = 0; i < 4; ++i) {
      gl_lds16(aP[i] + ke, &As[b][i * 1024 + ldst]);
      gl_lds16(bP[i] + ke, &Bs[b][i * 1024 + ldst]);
    }
  };

  const int NT = FDIM / 32;
  stage(0, 0);
  asm volatile("s_waitcnt vmcnt(0) lgkmcnt(0)" ::: "memory"); BAR();
  for (int t = 0; t < NT; ++t) {
    const int cur = t & 1;
    if (t + 1 < NT) stage(t + 1, cur ^ 1);
    bf16x8 af[8], bfv[4];
#pragma unroll
    for (int i = 0; i < 8; ++i) af[i] = *(const bf16x8*)&As[cur][(i * 16 + fr) * 32 + rdoff];
#pragma unroll
    for (int j = 0; j < 4; ++j) bfv[j] = *(const bf16x8*)&Bs[cur][(w * 64 + j * 16 + fr) * 32 + rdoff];
#pragma unroll
    for (int i = 0; i < 8; ++i)
#pragma unroll
      for (int j = 0; j < 4; ++j)
        acc[i][j] = __builtin_amdgcn_mfma_f32_16x16x32_bf16(af[i], bfv[j], acc[i][j], 0, 0, 0);
    if (t + 1 < NT) { asm volatile("s_waitcnt vmcnt(0) lgkmcnt(0)" ::: "memory"); BAR(); }
  }
#pragma unroll
  for (int i = 0; i < 8; ++i)
#pragma unroll
    for (int r = 0; r < 4; ++r) {
      const int row = i * 16 + (lane >> 4) * 4 + r;
      const int tk = toks[row];
      if (tk < 0) continue;
      float* yrow = yout + (size_t)tk * DDIM + n0;
#pragma unroll
      for (int j = 0; j < 4; ++j) {
        const int col = w * 64 + j * 16 + fr;
        yrow[col] += acc[i][j][r];
      }
    }
}

extern "C" void kernel_launch(void* const* d_in, const int* in_sizes, int n_in,
                              void* d_out, int out_size, void* d_ws, size_t ws_size,
                              hipStream_t stream) {
  (void)in_sizes; (void)n_in; (void)out_size;
  const float* x    = (const float*)d_in[0];
  const float* prev = (const float*)d_in[1];
  const float* Wt   = (const float*)d_in[2];
  const float* Wgt  = (const float*)d_in[3];
  const float* Wel  = (const float*)d_in[4];
  const float* W1   = (const float*)d_in[5];
  const float* b1   = (const float*)d_in[6];
  const float* W2   = (const float*)d_in[7];
  const float* b2   = (const float*)d_in[8];

  float* y      = (float*)d_out;
  float* logits = y + (size_t)NTOK * DDIM;

  char* ws = (char*)d_ws;
  size_t pos = 0;
  auto take = [&](size_t bytes) -> char* {
    char* r = ws + pos; pos += (bytes + 255) & ~(size_t)255; return r;
  };
  float* gn            = (float*)take((size_t)NTOK * NEXP * 4);
  int* cnt             = (int*)take(64);
  int* offs            = (int*)take(64);
  int* rowtok          = (int*)take((size_t)MAXROWS * 4);
  int* rowof           = (int*)take((size_t)NTOK * NEXP * 4);
  unsigned short* xb   = (unsigned short*)take((size_t)NTOK * DDIM * 2);
  const size_t fixed = pos;

  const size_t wexp = (size_t)FDIM * DDIM;
  const size_t needA = fixed + 2 * NEXP * wexp * 2 + (size_t)MAXROWS * FDIM * 2
                       + (size_t)MAXROWS * DDIM * 2 + 4096;
  const bool tierA = ws_size >= needA;

  router_kernel<<<dim3(NTOK / 4), dim3(256), 0, stream>>>(x, prev, Wt, Wgt, Wel, gn, logits);
  cast_kernel<<<dim3((NTOK * DDIM) / (8 * 256)), dim3(256), 0, stream>>>(x, xb);
  count_kernel<<<dim3(NEXP), dim3(256), 0, stream>>>(gn, cnt);
  compact_kernel<<<dim3(NEXP), dim3(256), 0, stream>>>(gn, cnt, offs, rowtok, rowof);

  if (tierA) {
    unsigned short* W1b = (unsigned short*)take(NEXP * wexp * 2);
    unsigned short* W2b = (unsigned short*)take(NEXP * wexp * 2);
    unsigned short* hb  = (unsigned short*)take((size_t)MAXROWS * FDIM * 2);
    unsigned short* hb2 = (unsigned short*)take((size_t)MAXROWS * DDIM * 2);

    transcvt<<<dim3(FDIM / 64, DDIM / 64, NEXP), dim3(256), 0, stream>>>(W1, W1b, DDIM, FDIM);
    transcvt<<<dim3(DDIM / 64, FDIM / 64, NEXP), dim3(256), 0, stream>>>(W2, W2b, FDIM, DDIM);
    gemm_h256<<<dim3(FDIM / 256, MAXROWS / 256), dim3(512), 0, stream>>>(
        xb, W1b, b1, gn, rowtok, offs, hb);
    gemm_o256<<<dim3(DDIM / 256, MAXROWS / 256), dim3(512), 0, stream>>>(
        hb, W2b, offs, hb2);
    combine_kernel<<<dim3(DDIM / 256, NTOK), dim3(256), 0, stream>>>(hb2, rowof, gn, b2, y);
  } else {
    unsigned short* Wb = (unsigned short*)take(wexp * 2);
    unsigned short* hb = (unsigned short*)take((size_t)NTOK * FDIM * 2);

    y_init_kernel<<<dim3(DDIM / 256, NTOK), dim3(256), 0, stream>>>(gn, b2, y);
    for (int e = 0; e < NEXP; ++e) {
      transcvt<<<dim3(FDIM / 64, DDIM / 64, 1), dim3(256), 0, stream>>>(
          W1 + (size_t)e * wexp, Wb, DDIM, FDIM);
      gemm_h128<<<dim3(FDIM / 128, 64), dim3(128), 0, stream>>>(
          xb, Wb, b1, gn, rowtok, offs, e, hb);
      transcvt<<<dim3(DDIM / 64, FDIM / 64, 1), dim3(256), 0, stream>>>(
          W2 + (size_t)e * wexp, Wb, FDIM, DDIM);
      gemm_o128<<<dim3(DDIM / 128, 64), dim3(128), 0, stream>>>(
          hb, Wb, rowtok, offs, e, y);
    }
  }
}

// Round 14
// 500.729 us; speedup vs baseline: 1.0159x; 1.0159x over previous
//
#include <hip/hip_runtime.h>
#include <math.h>

#define NTOK 8192   // B*S
#define DDIM 1024
#define NEXP 8
#define FDIM 4096
#define MAXROWS 26624   // <=3 active experts/token + per-expert pad-to-256

typedef short bf16x8 __attribute__((ext_vector_type(8)));
typedef float f32x4 __attribute__((ext_vector_type(4)));

#define BAR() asm volatile("s_barrier" ::: "memory")
#define WAITV(n) asm volatile("s_waitcnt vmcnt(" #n ")" ::: "memory")

static __device__ __forceinline__ unsigned short f2bf(float f) {
  unsigned int u = __float_as_uint(f);
  u += 0x7fffu + ((u >> 16) & 1u);
  return (unsigned short)(u >> 16);
}
static __device__ __forceinline__ float bf2f(unsigned short b) {
  return __uint_as_float(((unsigned int)b) << 16);
}

static __device__ __forceinline__ void gl_lds16(const void* g, void* l) {
  __builtin_amdgcn_global_load_lds(
      (const __attribute__((address_space(1))) unsigned int*)g,
      (__attribute__((address_space(3))) unsigned int*)l, 16, 0, 0);
}

// tanh-form gelu via exp2 (max abs err ~4e-4 vs erf form)
static __device__ __forceinline__ float gelu_f(float v) {
  float x2 = v * v;
  float p = fmaf(x2, 0.10294422f, 2.3021183f);
  float E = __builtin_amdgcn_exp2f(v * p);
  return v - v * __builtin_amdgcn_rcpf(E + 1.f);
}

// ---------------- router (fp32, mask-exact) ----------------
__global__ __launch_bounds__(256) void router_kernel(
    const float* __restrict__ x, const float* __restrict__ prev,
    const float* __restrict__ Wt, const float* __restrict__ Wgt,
    const float* __restrict__ Wel,
    float* __restrict__ gn, float* __restrict__ logits_out)
{
  __shared__ float wt_s[NEXP * DDIM];
  const int tid = threadIdx.x;
  for (int i = tid; i < NEXP * DDIM; i += 256) wt_s[i] = Wt[i];
  __syncthreads();
  const int lane = tid & 63;
  const int t = blockIdx.x * 4 + (tid >> 6);

  const float* xr = x + (size_t)t * DDIM;
  float acc[NEXP];
#pragma unroll
  for (int e = 0; e < NEXP; ++e) acc[e] = 0.f;
  for (int k = lane; k < DDIM; k += 64) {
    float xv = xr[k];
#pragma unroll
    for (int e = 0; e < NEXP; ++e) acc[e] += xv * wt_s[e * DDIM + k];
  }
#pragma unroll
  for (int e = 0; e < NEXP; ++e) {
    float v = acc[e];
#pragma unroll
    for (int off = 32; off >= 1; off >>= 1) v += __shfl_xor(v, off);
    acc[e] = v;
  }
  float pl[NEXP];
#pragma unroll
  for (int e = 0; e < NEXP; ++e) pl[e] = prev[(size_t)t * NEXP + e];
#pragma unroll
  for (int e = 0; e < NEXP; ++e) {
    float s = acc[e];
#pragma unroll
    for (int e2 = 0; e2 < NEXP; ++e2) s += pl[e2] * Wgt[e * NEXP + e2];
    acc[e] = s;
  }
  float mx = acc[0];
#pragma unroll
  for (int e = 1; e < NEXP; ++e) mx = fmaxf(mx, acc[e]);
  float st[NEXP]; float se = 0.f;
#pragma unroll
  for (int e = 0; e < NEXP; ++e) { st[e] = expf(acc[e] - mx); se += st[e]; }
  float inv = 1.f / se;
  float g[NEXP]; float gs = 0.f;
#pragma unroll
  for (int e = 0; e < NEXP; ++e) {
    float s = st[e] * inv;
    float we = 1.f / (1.f + expf(-Wel[e]));
    float gg = (s > 0.5f * we) ? s : 0.f;
    g[e] = gg; gs += gg;
  }
  float r = 1.f / (gs + 1e-6f);
  if (lane < NEXP) {
    gn[(size_t)t * NEXP + lane] = g[lane] * r;
    logits_out[(size_t)t * NEXP + lane] = acc[lane];
  }
}

// ---------------- x f32 -> bf16 ----------------
__global__ __launch_bounds__(256) void cast_kernel(
    const float* __restrict__ in, unsigned short* __restrict__ out)
{
  size_t i = ((size_t)blockIdx.x * 256 + threadIdx.x) * 8;
  float4 a = *(const float4*)(in + i);
  float4 b = *(const float4*)(in + i + 4);
  unsigned short tb[8];
  tb[0]=f2bf(a.x); tb[1]=f2bf(a.y); tb[2]=f2bf(a.z); tb[3]=f2bf(a.w);
  tb[4]=f2bf(b.x); tb[5]=f2bf(b.y); tb[6]=f2bf(b.z); tb[7]=f2bf(b.w);
  *(uint4*)(out + i) = *(const uint4*)tb;
}

// ---------------- count active tokens per expert ----------------
__global__ __launch_bounds__(256) void count_kernel(
    const float* __restrict__ gn, int* __restrict__ cnt)
{
  const int e = blockIdx.x, tid = threadIdx.x;
  int c = 0;
  for (int t = tid; t < NTOK; t += 256) c += (gn[(size_t)t * NEXP + e] > 0.f) ? 1 : 0;
#pragma unroll
  for (int o = 32; o >= 1; o >>= 1) c += __shfl_xor(c, o);
  __shared__ int sm[4];
  if ((tid & 63) == 0) sm[tid >> 6] = c;
  __syncthreads();
  if (tid == 0) cnt[e] = sm[0] + sm[1] + sm[2] + sm[3];
}

// ---------------- compact token lists (deterministic, token order; pad 256) ----------------
__global__ __launch_bounds__(256) void compact_kernel(
    const float* __restrict__ gn, const int* __restrict__ cnt,
    int* __restrict__ offs, int* __restrict__ rowtok, int* __restrict__ rowof)
{
  const int e = blockIdx.x, tid = threadIdx.x;
  int base = 0;
#pragma unroll
  for (int q = 0; q < 8; ++q) if (q < e) base += (cnt[q] + 255) & ~255;
  const int padcnt = (cnt[e] + 255) & ~255;
  if (e == 0 && tid == 0) {
    int a = 0; offs[0] = 0;
#pragma unroll
    for (int q = 0; q < 8; ++q) { a += (cnt[q] + 255) & ~255; offs[q + 1] = a; }
  }
  __shared__ int wsm[4];
  __shared__ int running;
  if (tid == 0) running = 0;
  __syncthreads();
  const int lane = tid & 63, wv = tid >> 6;
  for (int c0 = 0; c0 < NTOK; c0 += 256) {
    const int t = c0 + tid;
    const bool pr = gn[(size_t)t * NEXP + e] > 0.f;
    unsigned long long bal = __ballot(pr);
    int pre = __popcll(bal & ((1ull << lane) - 1ull));
    if (lane == 0) wsm[wv] = __popcll(bal);
    __syncthreads();
    int wbase = 0;
#pragma unroll
    for (int q = 0; q < 4; ++q) if (q < wv) wbase += wsm[q];
    const int tot = wsm[0] + wsm[1] + wsm[2] + wsm[3];
    const int idx = base + running + wbase + pre;
    if (pr) rowtok[idx] = t;
    rowof[(size_t)t * NEXP + e] = pr ? idx : -1;
    __syncthreads();
    if (tid == 0) running += tot;
  }
  __syncthreads();
  for (int i = cnt[e] + tid; i < padcnt; i += 256) rowtok[base + i] = -1;
}

// ---------------- y := sum_e gn*b2 (per-expert fallback path) ----------------
__global__ __launch_bounds__(256) void y_init_kernel(
    const float* __restrict__ gn, const float* __restrict__ b2,
    float* __restrict__ y)
{
  const int t = blockIdx.y;
  const int d = blockIdx.x * 256 + threadIdx.x;
  float s = 0.f;
#pragma unroll
  for (int e = 0; e < NEXP; ++e) s += gn[(size_t)t * NEXP + e] * b2[(size_t)e * DDIM + d];
  y[(size_t)t * DDIM + d] = s;
}

// ---------------- transpose+convert: in f32 [Kin][Nin] -> out bf16 [Nin][Kin] ----------------
__global__ __launch_bounds__(256) void transcvt(
    const float* __restrict__ in, unsigned short* __restrict__ out,
    int Kin, int Nin)
{
  __shared__ float tile[64][65];
  const size_t zo = (size_t)blockIdx.z * Kin * Nin;
  const float* inp = in + zo;
  unsigned short* outp = out + zo;
  const int k0 = blockIdx.y * 64, n0 = blockIdx.x * 64;
  const int tid = threadIdx.x;
  const int r = tid >> 4, c4 = (tid & 15) * 4;
#pragma unroll
  for (int rr = 0; rr < 64; rr += 16) {
    float4 v = *(const float4*)(inp + (size_t)(k0 + r + rr) * Nin + n0 + c4);
    tile[r + rr][c4] = v.x; tile[r + rr][c4 + 1] = v.y;
    tile[r + rr][c4 + 2] = v.z; tile[r + rr][c4 + 3] = v.w;
  }
  __syncthreads();
#pragma unroll
  for (int it = 0; it < 2; ++it) {
    const int o = it * 256 + tid;
    const int n = o >> 3, ks = (o & 7) * 8;
    unsigned short tb[8];
#pragma unroll
    for (int j = 0; j < 8; ++j) tb[j] = f2bf(tile[ks + j][n]);
    *(uint4*)(outp + (size_t)(n0 + n) * Kin + k0 + ks) = *(const uint4*)tb;
  }
}

// ===================== 256x256 4-phase GEMM kernels (grouped path, best-measured R12) =====
// 512 threads = 8 waves (2M x 4N); wave tile 128x64; acc[8][4]; BK=64.
// LDS: As/Bs [2][256*64] bf16 = 128 KB double-buffered.
// XOR swizzle: 16B-group slot = g ^ (row&7); gl_lds dest linear, SOURCE inverse-swizzled
// (verified: 0 bank conflicts). NO XCD swizzle (R8-R11: 2x regression on this grid).
// Per K-tile: 4 phases, stages 2,2,2,2 interleaved with MFMA quadrants; counted
// vmcnt(2) at P1 only; release barrier at P4. R13's reorder (4-at-P1/vmcnt(4)) was
// null -> this structure is the measured local optimum (501 us end-to-end).

// ---------------- GEMM1: h' = gn * gelu(gather(xb) @ W1^T + b1) -> hb bf16 ----------------
__global__ __launch_bounds__(512, 2) void gemm_h256(
    const unsigned short* __restrict__ xb,   // [NTOK][DDIM] bf16
    const unsigned short* __restrict__ W,    // [E][FDIM][DDIM] bf16 (transposed)
    const float* __restrict__ b1,            // [E][FDIM]
    const float* __restrict__ gn,            // [NTOK][E]
    const int* __restrict__ rowtok,
    const int* __restrict__ offs,            // [9], multiples of 256
    unsigned short* __restrict__ hb)         // [MAXROWS][FDIM] bf16
{
  __shared__ unsigned short As[2][256 * 64];
  __shared__ unsigned short Bs[2][256 * 64];
  __shared__ float gns[256];
  __shared__ float b1s[256];
  __shared__ int toks[256];
  const int tid = threadIdx.x;
  const int r0 = blockIdx.y * 256;
  if (r0 >= offs[8]) return;
  int e = 0;
#pragma unroll
  for (int q = 1; q < 8; ++q) if (r0 >= offs[q]) e = q;
  const int n0 = blockIdx.x * 256;
  const unsigned short* We = W + (size_t)e * FDIM * DDIM;

  if (tid < 256) {
    const int tk = rowtok[r0 + tid];
    toks[tid] = tk;
    gns[tid] = (tk >= 0) ? gn[(size_t)tk * NEXP + e] : 0.f;
    b1s[tid] = b1[(size_t)e * FDIM + n0 + tid];
  }
  __syncthreads();

  // staging: thread -> (chunk row rc, lds group gld); source group inverse-swizzled
  const int rc = tid >> 3;
  const int gld = tid & 7;
  const int gsrc = gld ^ (rc & 7);
  const unsigned short* aP[4];
  const unsigned short* bP[4];
#pragma unroll
  for (int c = 0; c < 4; ++c) {
    int tk = toks[c * 64 + rc]; if (tk < 0) tk = 0;
    aP[c] = xb + (size_t)tk * DDIM + gsrc * 8;
    bP[c] = We + (size_t)(n0 + c * 64 + rc) * DDIM + gsrc * 8;
  }

  const int lane = tid & 63;
  const int wid = tid >> 6;
  const int wm = (wid >> 2) * 128;
  const int wn = (wid & 3) * 64;
  const int fr = lane & 15;
  const int q4 = lane >> 4;

  f32x4 acc[8][4];
#pragma unroll
  for (int i = 0; i < 8; ++i)
#pragma unroll
    for (int j = 0; j < 4; ++j) acc[i][j] = (f32x4){0.f, 0.f, 0.f, 0.f};

  auto stA = [&](int kt, int b, int c) { gl_lds16(aP[c] + kt * 64, &As[b][c * 4096 + tid * 8]); };
  auto stB = [&](int kt, int b, int c) { gl_lds16(bP[c] + kt * 64, &Bs[b][c * 4096 + tid * 8]); };
  auto rdA = [&](int cur, int i, int kk) -> bf16x8 {
    const int row = wm + i * 16 + fr;
    const int sl = (kk * 4 + q4) ^ (row & 7);
    return *(const bf16x8*)&As[cur][row * 64 + sl * 8];
  };
  auto rdB = [&](int cur, int j, int kk) -> bf16x8 {
    const int row = wn + j * 16 + fr;
    const int sl = (kk * 4 + q4) ^ (row & 7);
    return *(const bf16x8*)&Bs[cur][row * 64 + sl * 8];
  };

  const int NT = DDIM / 64;   // 16
  bf16x8 aX[4][2], aY[4][2], bb[2][2];

#pragma unroll
  for (int c = 0; c < 4; ++c) { stA(0, 0, c); stB(0, 0, c); }
  WAITV(0); BAR();

  for (int t = 0; t < NT - 1; ++t) {
    const int cur = t & 1, nxt = cur ^ 1;
    // P1: stage 2 | read A0,B0 | MFMA A0xB0
    stA(t + 1, nxt, 0); stA(t + 1, nxt, 1);
    WAITV(2); BAR();
#pragma unroll
    for (int i = 0; i < 4; ++i) { aX[i][0] = rdA(cur, i, 0); aX[i][1] = rdA(cur, i, 1); }
#pragma unroll
    for (int j = 0; j < 2; ++j) { bb[j][0] = rdB(cur, j, 0); bb[j][1] = rdB(cur, j, 1); }
    __builtin_amdgcn_s_setprio(1);
#pragma unroll
    for (int i = 0; i < 4; ++i)
#pragma unroll
      for (int j = 0; j < 2; ++j)
#pragma unroll
        for (int kk = 0; kk < 2; ++kk)
          acc[i][j] = __builtin_amdgcn_mfma_f32_16x16x32_bf16(aX[i][kk], bb[j][kk], acc[i][j], 0, 0, 0);
    __builtin_amdgcn_s_setprio(0);
    // P2: stage 2 | read A1 | MFMA A1xB0
    stA(t + 1, nxt, 2); stA(t + 1, nxt, 3);
#pragma unroll
    for (int i = 0; i < 4; ++i) { aY[i][0] = rdA(cur, 4 + i, 0); aY[i][1] = rdA(cur, 4 + i, 1); }
    __builtin_amdgcn_s_setprio(1);
#pragma unroll
    for (int i = 0; i < 4; ++i)
#pragma unroll
      for (int j = 0; j < 2; ++j)
#pragma unroll
        for (int kk = 0; kk < 2; ++kk)
          acc[4 + i][j] = __builtin_amdgcn_mfma_f32_16x16x32_bf16(aY[i][kk], bb[j][kk], acc[4 + i][j], 0, 0, 0);
    __builtin_amdgcn_s_setprio(0);
    // P3: stage 2 | read B1 | MFMA A1xB1
    stB(t + 1, nxt, 0); stB(t + 1, nxt, 1);
#pragma unroll
    for (int j = 0; j < 2; ++j) { bb[j][0] = rdB(cur, 2 + j, 0); bb[j][1] = rdB(cur, 2 + j, 1); }
    __builtin_amdgcn_s_setprio(1);
#pragma unroll
    for (int i = 0; i < 4; ++i)
#pragma unroll
      for (int j = 0; j < 2; ++j)
#pragma unroll
        for (int kk = 0; kk < 2; ++kk)
          acc[4 + i][2 + j] = __builtin_amdgcn_mfma_f32_16x16x32_bf16(aY[i][kk], bb[j][kk], acc[4 + i][2 + j], 0, 0, 0);
    __builtin_amdgcn_s_setprio(0);
    // P4: stage 2 | MFMA A0xB1 | release barrier
    stB(t + 1, nxt, 2); stB(t + 1, nxt, 3);
    __builtin_amdgcn_s_setprio(1);
#pragma unroll
    for (int i = 0; i < 4; ++i)
#pragma unroll
      for (int j = 0; j < 2; ++j)
#pragma unroll
        for (int kk = 0; kk < 2; ++kk)
          acc[i][2 + j] = __builtin_amdgcn_mfma_f32_16x16x32_bf16(aX[i][kk], bb[j][kk], acc[i][2 + j], 0, 0, 0);
    __builtin_amdgcn_s_setprio(0);
    BAR();
  }
  // tail tile (no staging)
  {
    const int cur = (NT - 1) & 1;
    WAITV(0); BAR();
#pragma unroll
    for (int i = 0; i < 4; ++i) { aX[i][0] = rdA(cur, i, 0); aX[i][1] = rdA(cur, i, 1); }
#pragma unroll
    for (int i = 0; i < 4; ++i) { aY[i][0] = rdA(cur, 4 + i, 0); aY[i][1] = rdA(cur, 4 + i, 1); }
#pragma unroll
    for (int j = 0; j < 2; ++j) { bb[j][0] = rdB(cur, j, 0); bb[j][1] = rdB(cur, j, 1); }
#pragma unroll
    for (int i = 0; i < 4; ++i)
#pragma unroll
      for (int j = 0; j < 2; ++j)
#pragma unroll
        for (int kk = 0; kk < 2; ++kk) {
          acc[i][j] = __builtin_amdgcn_mfma_f32_16x16x32_bf16(aX[i][kk], bb[j][kk], acc[i][j], 0, 0, 0);
          acc[4 + i][j] = __builtin_amdgcn_mfma_f32_16x16x32_bf16(aY[i][kk], bb[j][kk], acc[4 + i][j], 0, 0, 0);
        }
#pragma unroll
    for (int j = 0; j < 2; ++j) { bb[j][0] = rdB(cur, 2 + j, 0); bb[j][1] = rdB(cur, 2 + j, 1); }
#pragma unroll
    for (int i = 0; i < 4; ++i)
#pragma unroll
      for (int j = 0; j < 2; ++j)
#pragma unroll
        for (int kk = 0; kk < 2; ++kk) {
          acc[i][2 + j] = __builtin_amdgcn_mfma_f32_16x16x32_bf16(aX[i][kk], bb[j][kk], acc[i][2 + j], 0, 0, 0);
          acc[4 + i][2 + j] = __builtin_amdgcn_mfma_f32_16x16x32_bf16(aY[i][kk], bb[j][kk], acc[4 + i][2 + j], 0, 0, 0);
        }
  }

#pragma unroll
  for (int i = 0; i < 8; ++i)
#pragma unroll
    for (int rr = 0; rr < 4; ++rr) {
      const int row = wm + i * 16 + q4 * 4 + rr;
      const int tk = toks[row];
      if (tk < 0) continue;
      const float gv = gns[row];
      unsigned short* hrow = hb + (size_t)(r0 + row) * FDIM + n0;
#pragma unroll
      for (int j = 0; j < 4; ++j) {
        const int col = wn + j * 16 + fr;
        hrow[col] = f2bf(gelu_f(acc[i][j][rr] + b1s[col]) * gv);
      }
    }
}

// ---------------- GEMM2: hb2 = hb @ W2^T (bf16 partials, grouped) ----------------
__global__ __launch_bounds__(512, 2) void gemm_o256(
    const unsigned short* __restrict__ hb,   // [MAXROWS][FDIM] bf16
    const unsigned short* __restrict__ W,    // [E][DDIM][FDIM] bf16 (transposed)
    const int* __restrict__ offs,
    unsigned short* __restrict__ hb2)        // [MAXROWS][DDIM] bf16
{
  __shared__ unsigned short As[2][256 * 64];
  __shared__ unsigned short Bs[2][256 * 64];
  const int tid = threadIdx.x;
  const int r0 = blockIdx.y * 256;
  if (r0 >= offs[8]) return;
  int e = 0;
#pragma unroll
  for (int q = 1; q < 8; ++q) if (r0 >= offs[q]) e = q;
  const int n0 = blockIdx.x * 256;
  const unsigned short* We = W + (size_t)e * FDIM * DDIM;

  const int rc = tid >> 3;
  const int gld = tid & 7;
  const int gsrc = gld ^ (rc & 7);
  const unsigned short* aP[4];
  const unsigned short* bP[4];
#pragma unroll
  for (int c = 0; c < 4; ++c) {
    aP[c] = hb + (size_t)(r0 + c * 64 + rc) * FDIM + gsrc * 8;
    bP[c] = We + (size_t)(n0 + c * 64 + rc) * FDIM + gsrc * 8;
  }

  const int lane = tid & 63;
  const int wid = tid >> 6;
  const int wm = (wid >> 2) * 128;
  const int wn = (wid & 3) * 64;
  const int fr = lane & 15;
  const int q4 = lane >> 4;

  f32x4 acc[8][4];
#pragma unroll
  for (int i = 0; i < 8; ++i)
#pragma unroll
    for (int j = 0; j < 4; ++j) acc[i][j] = (f32x4){0.f, 0.f, 0.f, 0.f};

  auto stA = [&](int kt, int b, int c) { gl_lds16(aP[c] + kt * 64, &As[b][c * 4096 + tid * 8]); };
  auto stB = [&](int kt, int b, int c) { gl_lds16(bP[c] + kt * 64, &Bs[b][c * 4096 + tid * 8]); };
  auto rdA = [&](int cur, int i, int kk) -> bf16x8 {
    const int row = wm + i * 16 + fr;
    const int sl = (kk * 4 + q4) ^ (row & 7);
    return *(const bf16x8*)&As[cur][row * 64 + sl * 8];
  };
  auto rdB = [&](int cur, int j, int kk) -> bf16x8 {
    const int row = wn + j * 16 + fr;
    const int sl = (kk * 4 + q4) ^ (row & 7);
    return *(const bf16x8*)&Bs[cur][row * 64 + sl * 8];
  };

  const int NT = FDIM / 64;   // 64
  bf16x8 aX[4][2], aY[4][2], bb[2][2];

#pragma unroll
  for (int c = 0; c < 4; ++c) { stA(0, 0, c); stB(0, 0, c); }
  WAITV(0); BAR();

  for (int t = 0; t < NT - 1; ++t) {
    const int cur = t & 1, nxt = cur ^ 1;
    stA(t + 1, nxt, 0); stA(t + 1, nxt, 1);
    WAITV(2); BAR();
#pragma unroll
    for (int i = 0; i < 4; ++i) { aX[i][0] = rdA(cur, i, 0); aX[i][1] = rdA(cur, i, 1); }
#pragma unroll
    for (int j = 0; j < 2; ++j) { bb[j][0] = rdB(cur, j, 0); bb[j][1] = rdB(cur, j, 1); }
    __builtin_amdgcn_s_setprio(1);
#pragma unroll
    for (int i = 0; i < 4; ++i)
#pragma unroll
      for (int j = 0; j < 2; ++j)
#pragma unroll
        for (int kk = 0; kk < 2; ++kk)
          acc[i][j] = __builtin_amdgcn_mfma_f32_16x16x32_bf16(aX[i][kk], bb[j][kk], acc[i][j], 0, 0, 0);
    __builtin_amdgcn_s_setprio(0);
    stA(t + 1, nxt, 2); stA(t + 1, nxt, 3);
#pragma unroll
    for (int i = 0; i < 4; ++i) { aY[i][0] = rdA(cur, 4 + i, 0); aY[i][1] = rdA(cur, 4 + i, 1); }
    __builtin_amdgcn_s_setprio(1);
#pragma unroll
    for (int i = 0; i < 4; ++i)
#pragma unroll
      for (int j = 0; j < 2; ++j)
#pragma unroll
        for (int kk = 0; kk < 2; ++kk)
          acc[4 + i][j] = __builtin_amdgcn_mfma_f32_16x16x32_bf16(aY[i][kk], bb[j][kk], acc[4 + i][j], 0, 0, 0);
    __builtin_amdgcn_s_setprio(0);
    stB(t + 1, nxt, 0); stB(t + 1, nxt, 1);
#pragma unroll
    for (int j = 0; j < 2; ++j) { bb[j][0] = rdB(cur, 2 + j, 0); bb[j][1] = rdB(cur, 2 + j, 1); }
    __builtin_amdgcn_s_setprio(1);
#pragma unroll
    for (int i = 0; i < 4; ++i)
#pragma unroll
      for (int j = 0; j < 2; ++j)
#pragma unroll
        for (int kk = 0; kk < 2; ++kk)
          acc[4 + i][2 + j] = __builtin_amdgcn_mfma_f32_16x16x32_bf16(aY[i][kk], bb[j][kk], acc[4 + i][2 + j], 0, 0, 0);
    __builtin_amdgcn_s_setprio(0);
    stB(t + 1, nxt, 2); stB(t + 1, nxt, 3);
    __builtin_amdgcn_s_setprio(1);
#pragma unroll
    for (int i = 0; i < 4; ++i)
#pragma unroll
      for (int j = 0; j < 2; ++j)
#pragma unroll
        for (int kk = 0; kk < 2; ++kk)
          acc[i][2 + j] = __builtin_amdgcn_mfma_f32_16x16x32_bf16(aX[i][kk], bb[j][kk], acc[i][2 + j], 0, 0, 0);
    __builtin_amdgcn_s_setprio(0);
    BAR();
  }
  {
    const int cur = (NT - 1) & 1;
    WAITV(0); BAR();
#pragma unroll
    for (int i = 0; i < 4; ++i) { aX[i][0] = rdA(cur, i, 0); aX[i][1] = rdA(cur, i, 1); }
#pragma unroll
    for (int i = 0; i < 4; ++i) { aY[i][0] = rdA(cur, 4 + i, 0); aY[i][1] = rdA(cur, 4 + i, 1); }
#pragma unroll
    for (int j = 0; j < 2; ++j) { bb[j][0] = rdB(cur, j, 0); bb[j][1] = rdB(cur, j, 1); }
#pragma unroll
    for (int i = 0; i < 4; ++i)
#pragma unroll
      for (int j = 0; j < 2; ++j)
#pragma unroll
        for (int kk = 0; kk < 2; ++kk) {
          acc[i][j] = __builtin_amdgcn_mfma_f32_16x16x32_bf16(aX[i][kk], bb[j][kk], acc[i][j], 0, 0, 0);
          acc[4 + i][j] = __builtin_amdgcn_mfma_f32_16x16x32_bf16(aY[i][kk], bb[j][kk], acc[4 + i][j], 0, 0, 0);
        }
#pragma unroll
    for (int j = 0; j < 2; ++j) { bb[j][0] = rdB(cur, 2 + j, 0); bb[j][1] = rdB(cur, 2 + j, 1); }
#pragma unroll
    for (int i = 0; i < 4; ++i)
#pragma unroll
      for (int j = 0; j < 2; ++j)
#pragma unroll
        for (int kk = 0; kk < 2; ++kk) {
          acc[i][2 + j] = __builtin_amdgcn_mfma_f32_16x16x32_bf16(aX[i][kk], bb[j][kk], acc[i][2 + j], 0, 0, 0);
          acc[4 + i][2 + j] = __builtin_amdgcn_mfma_f32_16x16x32_bf16(aY[i][kk], bb[j][kk], acc[4 + i][2 + j], 0, 0, 0);
        }
  }

#pragma unroll
  for (int i = 0; i < 8; ++i)
#pragma unroll
    for (int rr = 0; rr < 4; ++rr) {
      const int row = wm + i * 16 + q4 * 4 + rr;
      unsigned short* orow = hb2 + (size_t)(r0 + row) * DDIM + n0;
#pragma unroll
      for (int j = 0; j < 4; ++j) {
        const int col = wn + j * 16 + fr;
        orow[col] = f2bf(acc[i][j][rr]);
      }
    }
}

// ---------------- combine: y = sum over active rows (bf16 partials) + gn*b2 ----------------
__global__ __launch_bounds__(256) void combine_kernel(
    const unsigned short* __restrict__ hb2, const int* __restrict__ rowof,
    const float* __restrict__ gn, const float* __restrict__ b2,
    float* __restrict__ y)
{
  const int t = blockIdx.y;
  const int d = blockIdx.x * 256 + threadIdx.x;
  float s = 0.f;
#pragma unroll
  for (int e = 0; e < NEXP; ++e) {
    s += gn[(size_t)t * NEXP + e] * b2[(size_t)e * DDIM + d];
    const int r = rowof[(size_t)t * NEXP + e];
    if (r >= 0) s += bf2f(hb2[(size_t)r * DDIM + d]);
  }
  y[(size_t)t * DDIM + d] = s;
}

// ===================== 128x128 fallback kernels (tier-B, per-expert) =====================
__global__ __launch_bounds__(128, 2) void gemm_h128(
    const unsigned short* __restrict__ xb,
    const unsigned short* __restrict__ W,
    const float* __restrict__ b1,
    const float* __restrict__ gn,
    const int* __restrict__ rowtok,
    const int* __restrict__ offs,
    int efix,
    unsigned short* __restrict__ hb)
{
  __shared__ unsigned short As[2][4096];
  __shared__ unsigned short Bs[2][4096];
  __shared__ float gns[128];
  __shared__ float b1s[128];
  __shared__ int toks[128];
  const int tid = threadIdx.x;
  const int e = efix;
  const int hbase = offs[e];
  const int mt = (hbase >> 7) + blockIdx.y;
  if (mt * 128 >= offs[e + 1]) return;
  const int n0 = blockIdx.x * 128;
  const unsigned short* We = W;

  {
    const int tk = rowtok[mt * 128 + tid];
    toks[tid] = tk;
    gns[tid] = (tk >= 0) ? gn[(size_t)tk * NEXP + e] : 0.f;
    b1s[tid] = b1[(size_t)e * FDIM + n0 + tid];
  }
  __syncthreads();

  const int st_row = tid >> 2;
  const int st_off = (((tid & 3) ^ (st_row & 3)) << 3);
  const unsigned short* aP[4];
  const unsigned short* bP[4];
#pragma unroll
  for (int i = 0; i < 4; ++i) {
    int tk = toks[i * 32 + st_row]; if (tk < 0) tk = 0;
    aP[i] = xb + (size_t)tk * DDIM + st_off;
    bP[i] = We + (size_t)(n0 + i * 32 + st_row) * DDIM + st_off;
  }
  const int ldst = tid * 8;
  const int lane = tid & 63;
  const int w = tid >> 6;
  const int fr = lane & 15;
  const int rdoff = (((lane >> 4) ^ (lane & 3)) << 3);

  f32x4 acc[8][4];
#pragma unroll
  for (int i = 0; i < 8; ++i)
#pragma unroll
    for (int j = 0; j < 4; ++j) acc[i][j] = (f32x4){0.f, 0.f, 0.f, 0.f};

  auto stage = [&](int kt, int b) {
    const int ke = kt * 32;
#pragma unroll
    for (int i = 0; i < 4; ++i) {
      gl_lds16(aP[i] + ke, &As[b][i * 1024 + ldst]);
      gl_lds16(bP[i] + ke, &Bs[b][i * 1024 + ldst]);
    }
  };

  const int NT = DDIM / 32;
  stage(0, 0);
  asm volatile("s_waitcnt vmcnt(0) lgkmcnt(0)" ::: "memory"); BAR();
  for (int t = 0; t < NT; ++t) {
    const int cur = t & 1;
    if (t + 1 < NT) stage(t + 1, cur ^ 1);
    bf16x8 af[8], bfv[4];
#pragma unroll
    for (int i = 0; i < 8; ++i) af[i] = *(const bf16x8*)&As[cur][(i * 16 + fr) * 32 + rdoff];
#pragma unroll
    for (int j = 0; j < 4; ++j) bfv[j] = *(const bf16x8*)&Bs[cur][(w * 64 + j * 16 + fr) * 32 + rdoff];
#pragma unroll
    for (int i = 0; i < 8; ++i)
#pragma unroll
      for (int j = 0; j < 4; ++j)
        acc[i][j] = __builtin_amdgcn_mfma_f32_16x16x32_bf16(af[i], bfv[j], acc[i][j], 0, 0, 0);
    if (t + 1 < NT) { asm volatile("s_waitcnt vmcnt(0) lgkmcnt(0)" ::: "memory"); BAR(); }
  }
#pragma unroll
  for (int i = 0; i < 8; ++i)
#pragma unroll
    for (int r = 0; r < 4; ++r) {
      const int row = i * 16 + (lane >> 4) * 4 + r;
      const int tk = toks[row];
      if (tk < 0) continue;
      const float gv = gns[row];
      unsigned short* hrow = hb + (size_t)(mt * 128 + row - hbase) * FDIM + n0;
#pragma unroll
      for (int j = 0; j < 4; ++j) {
        const int col = w * 64 + j * 16 + fr;
        hrow[col] = f2bf(gelu_f(acc[i][j][r] + b1s[col]) * gv);
      }
    }
}

__global__ __launch_bounds__(128, 2) void gemm_o128(
    const unsigned short* __restrict__ hb,
    const unsigned short* __restrict__ W,
    const int* __restrict__ rowtok,
    const int* __restrict__ offs,
    int efix,
    float* __restrict__ yout)
{
  __shared__ unsigned short As[2][4096];
  __shared__ unsigned short Bs[2][4096];
  __shared__ int toks[128];
  const int tid = threadIdx.x;
  const int e = efix;
  const int hbase = offs[e];
  const int mt = (hbase >> 7) + blockIdx.y;
  if (mt * 128 >= offs[e + 1]) return;
  const int n0 = blockIdx.x * 128;

  toks[tid] = rowtok[mt * 128 + tid];
  __syncthreads();

  const int st_row = tid >> 2;
  const int st_off = (((tid & 3) ^ (st_row & 3)) << 3);
  const unsigned short* aP[4];
  const unsigned short* bP[4];
#pragma unroll
  for (int i = 0; i < 4; ++i) {
    aP[i] = hb + (size_t)(mt * 128 - hbase + i * 32 + st_row) * FDIM + st_off;
    bP[i] = W + (size_t)(n0 + i * 32 + st_row) * FDIM + st_off;
  }
  const int ldst = tid * 8;
  const int lane = tid & 63;
  const int w = tid >> 6;
  const int fr = lane & 15;
  const int rdoff = (((lane >> 4) ^ (lane & 3)) << 3);

  f32x4 acc[8][4];
#pragma unroll
  for (int i = 0; i < 8; ++i)
#pragma unroll
    for (int j = 0; j < 4; ++j) acc[i][j] = (f32x4){0.f, 0.f, 0.f, 0.f};

  auto stage = [&](int kt, int b) {
    const int ke = kt * 32;
#pragma unroll
    for (int i = 0; i < 4; ++i) {
      gl_lds16(aP[i] + ke, &As[b][i * 1024 + ldst]);
      gl_lds16(bP[i] + ke, &Bs[b][i * 1024 + ldst]);
    }
  };

  const int NT = FDIM / 32;
  stage(0, 0);
  asm volatile("s_waitcnt vmcnt(0) lgkmcnt(0)" ::: "memory"); BAR();
  for (int t = 0; t < NT; ++t) {
    const int cur = t & 1;
    if (t + 1 < NT) stage(t + 1, cur ^ 1);
    bf16x8 af[8], bfv[4];
#pragma unroll
    for (int i = 0; i < 8; ++i) af[i] = *(const bf16x8*)&As[cur][(i * 16 + fr) * 32 + rdoff];
#pragma unroll
    for (int j = 0; j < 4; ++j) bfv[j] = *(const bf16x8*)&Bs[cur][(w * 64 + j * 16 + fr) * 32 + rdoff];
#pragma unroll
    for (int i = 0; i < 8; ++i)
#pragma unroll
      for (int j = 0; j < 4; ++j)
        acc[i][j] = __builtin_amdgcn_mfma_f32_16x16x32_bf16(af[i], bfv[j], acc[i][j], 0, 0, 0);
    if (t + 1 < NT) { asm volatile("s_waitcnt vmcnt(0) lgkmcnt(0)" ::: "memory"); BAR(); }
  }
#pragma unroll
  for (int i = 0; i < 8; ++i)
#pragma unroll
    for (int r = 0; r < 4; ++r) {
      const int row = i * 16 + (lane >> 4) * 4 + r;
      const int tk = toks[row];
      if (tk < 0) continue;
      float* yrow = yout + (size_t)tk * DDIM + n0;
#pragma unroll
      for (int j = 0; j < 4; ++j) {
        const int col = w * 64 + j * 16 + fr;
        yrow[col] += acc[i][j][r];
      }
    }
}

extern "C" void kernel_launch(void* const* d_in, const int* in_sizes, int n_in,
                              void* d_out, int out_size, void* d_ws, size_t ws_size,
                              hipStream_t stream) {
  (void)in_sizes; (void)n_in; (void)out_size;
  const float* x    = (const float*)d_in[0];
  const float* prev = (const float*)d_in[1];
  const float* Wt   = (const float*)d_in[2];
  const float* Wgt  = (const float*)d_in[3];
  const float* Wel  = (const float*)d_in[4];
  const float* W1   = (const float*)d_in[5];
  const float* b1   = (const float*)d_in[6];
  const float* W2   = (const float*)d_in[7];
  const float* b2   = (const float*)d_in[8];

  float* y      = (float*)d_out;
  float* logits = y + (size_t)NTOK * DDIM;

  char* ws = (char*)d_ws;
  size_t pos = 0;
  auto take = [&](size_t bytes) -> char* {
    char* r = ws + pos; pos += (bytes + 255) & ~(size_t)255; return r;
  };
  float* gn            = (float*)take((size_t)NTOK * NEXP * 4);
  int* cnt             = (int*)take(64);
  int* offs            = (int*)take(64);
  int* rowtok          = (int*)take((size_t)MAXROWS * 4);
  int* rowof           = (int*)take((size_t)NTOK * NEXP * 4);
  unsigned short* xb   = (unsigned short*)take((size_t)NTOK * DDIM * 2);
  const size_t fixed = pos;

  const size_t wexp = (size_t)FDIM * DDIM;
  const size_t needA = fixed + 2 * NEXP * wexp * 2 + (size_t)MAXROWS * FDIM * 2
                       + (size_t)MAXROWS * DDIM * 2 + 4096;
  const bool tierA = ws_size >= needA;

  router_kernel<<<dim3(NTOK / 4), dim3(256), 0, stream>>>(x, prev, Wt, Wgt, Wel, gn, logits);
  cast_kernel<<<dim3((NTOK * DDIM) / (8 * 256)), dim3(256), 0, stream>>>(x, xb);
  count_kernel<<<dim3(NEXP), dim3(256), 0, stream>>>(gn, cnt);
  compact_kernel<<<dim3(NEXP), dim3(256), 0, stream>>>(gn, cnt, offs, rowtok, rowof);

  if (tierA) {
    unsigned short* W1b = (unsigned short*)take(NEXP * wexp * 2);
    unsigned short* W2b = (unsigned short*)take(NEXP * wexp * 2);
    unsigned short* hb  = (unsigned short*)take((size_t)MAXROWS * FDIM * 2);
    unsigned short* hb2 = (unsigned short*)take((size_t)MAXROWS * DDIM * 2);

    transcvt<<<dim3(FDIM / 64, DDIM / 64, NEXP), dim3(256), 0, stream>>>(W1, W1b, DDIM, FDIM);
    transcvt<<<dim3(DDIM / 64, FDIM / 64, NEXP), dim3(256), 0, stream>>>(W2, W2b, FDIM, DDIM);
    gemm_h256<<<dim3(FDIM / 256, MAXROWS / 256), dim3(512), 0, stream>>>(
        xb, W1b, b1, gn, rowtok, offs, hb);
    gemm_o256<<<dim3(DDIM / 256, MAXROWS / 256), dim3(512), 0, stream>>>(
        hb, W2b, offs, hb2);
    combine_kernel<<<dim3(DDIM / 256, NTOK), dim3(256), 0, stream>>>(hb2, rowof, gn, b2, y);
  } else {
    unsigned short* Wb = (unsigned short*)take(wexp * 2);
    unsigned short* hb = (unsigned short*)take((size_t)NTOK * FDIM * 2);

    y_init_kernel<<<dim3(DDIM / 256, NTOK), dim3(256), 0, stream>>>(gn, b2, y);
    for (int e = 0; e < NEXP; ++e) {
      transcvt<<<dim3(FDIM / 64, DDIM / 64, 1), dim3(256), 0, stream>>>(
          W1 + (size_t)e * wexp, Wb, DDIM, FDIM);
      gemm_h128<<<dim3(FDIM / 128, 64), dim3(128), 0, stream>>>(
          xb, Wb, b1, gn, rowtok, offs, e, hb);
      transcvt<<<dim3(DDIM / 64, FDIM / 64, 1), dim3(256), 0, stream>>>(
          W2 + (size_t)e * wexp, Wb, FDIM, DDIM);
      gemm_o128<<<dim3(DDIM / 128, 64), dim3(128), 0, stream>>>(
          hb, Wb, rowtok, offs, e, y);
    }
  }
}